// Round 3
// baseline (224.758 us; speedup 1.0000x reference)
//
#include <hip/hip_runtime.h>
#include <hip/hip_bf16.h>

#define BB     8
#define CC     320
#define NN     4096
#define SKV    77
#define DKV    1024
#define HEADS  8
#define DH     64
#define INNER  512
#define SCALE  0.125f
#define XSTR   330   // X_lds row stride (shorts): dword-stride 165, odd -> 2-way free

typedef float f32x4  __attribute__((ext_vector_type(4)));
typedef short bf16x8 __attribute__((ext_vector_type(8)));
typedef short s16x4  __attribute__((ext_vector_type(4)));
typedef short s16x2  __attribute__((ext_vector_type(2)));

static __device__ __forceinline__ short f2bf(float f) {
  unsigned u = __float_as_uint(f);
  return (short)((u + 0x7fffu + ((u >> 16) & 1u)) >> 16);
}

// 4B-aligned fragment load (X_lds rows are 4B- but not 16B-aligned)
static __device__ __forceinline__ bf16x8 ld_frag4(const short* p) {
  const s16x2 a = *(const s16x2*)(p);
  const s16x2 b = *(const s16x2*)(p + 2);
  const s16x2 c = *(const s16x2*)(p + 4);
  const s16x2 d = *(const s16x2*)(p + 6);
  bf16x8 r;
  r[0]=a[0]; r[1]=a[1]; r[2]=b[0]; r[3]=b[1];
  r[4]=c[0]; r[5]=c[1]; r[6]=d[0]; r[7]=d[1];
  return r;
}

// ---------------------------------------------------------------------------
// prep: kv->bf16 | Wk,Wv tiled LDS transpose -> bf16 | Wq_t,Wo_t strided |
// zero K_ws/V_ws pads.
// blocks: [0,616) kv | [616,744) Wk 64x64 tiles | [744,872) Wv tiles |
// [872,1384) Wq_t | [1384,1704) Wo_t | [1704,2144) zero
// ---------------------------------------------------------------------------
__global__ __launch_bounds__(256) void prep_kernel(
    const float* __restrict__ kv, const float* __restrict__ Wk,
    const float* __restrict__ Wv, const float* __restrict__ Wq,
    const float* __restrict__ Wo, short* __restrict__ kv_bf,
    short* __restrict__ Wk_t, short* __restrict__ Wv_t,
    short* __restrict__ Wq_t, short* __restrict__ Wo_t,
    unsigned* __restrict__ zero_base) {
  __shared__ float T[64 * 65];
  const int blk = blockIdx.x, t = threadIdx.x;
  if (blk < 616) {
    const int base = blk * 1024;
    #pragma unroll
    for (int i = 0; i < 4; ++i) kv_bf[base + i*256 + t] = f2bf(kv[base + i*256 + t]);
  } else if (blk < 872) {
    // 64x64 tile transpose: src [1024][512] -> dst [512][1024]
    const int tile = blk - 616;
    const bool isK = tile < 128;
    const int tt = isK ? tile : tile - 128;
    const int kt = tt >> 3, ct = tt & 7;          // k-tile 0..15, c-tile 0..7
    const float* __restrict__ src = isK ? Wk : Wv;
    short* __restrict__ dst = isK ? Wk_t : Wv_t;
    const int cl = t & 63, rb = t >> 6;
    #pragma unroll
    for (int i = 0; i < 16; ++i) {
      const int r = rb + i*4;
      T[r*65 + cl] = src[(size_t)(kt*64 + r)*512 + ct*64 + cl];   // coalesced read
    }
    __syncthreads();
    #pragma unroll
    for (int i = 0; i < 16; ++i) {
      const int nl = rb + i*4;
      dst[(size_t)(ct*64 + nl)*1024 + kt*64 + cl] = f2bf(T[cl*65 + nl]);
    }
  } else if (blk < 1384) {
    const int n = blk - 872;
    for (int c = t; c < 320; c += 256) Wq_t[n*320 + c] = f2bf(Wq[c*512 + n]);
  } else if (blk < 1704) {
    const int c = blk - 1384;
    for (int j = t; j < 512; j += 256) Wo_t[c*512 + j] = f2bf(Wo[j*320 + c]);
  } else {
    const int base = (blk - 1704) * 1024;
    #pragma unroll
    for (int i = 0; i < 4; ++i) zero_base[base + i*256 + t] = 0u;
  }
}

// ---------------------------------------------------------------------------
// kvproj: [616,1024]bf16 @ Wk_t/Wv_t -> K_ws [b][h][80][64], V_ws [b][h][64][96]
// ---------------------------------------------------------------------------
__global__ __launch_bounds__(256) void kvproj_kernel(
    const short* __restrict__ kv_bf, const short* __restrict__ Wk_t,
    const short* __restrict__ Wv_t, short* __restrict__ K_ws,
    short* __restrict__ V_ws) {
  const int t = threadIdx.x, w = t >> 6, lane = t & 63;
  const int l15 = lane & 15, q = lane >> 4;
  const int m0 = (blockIdx.x * 4 + w) * 16;
  const int y = blockIdx.y;
  const bool isK = (y < 8);
  const int h = y & 7;
  const short* __restrict__ Wt = isK ? Wk_t : Wv_t;
  const int arow = (m0 + l15 < 616) ? (m0 + l15) : 615;

  const f32x4 z = {0.f, 0.f, 0.f, 0.f};
  f32x4 acc[4] = {z, z, z, z};
  for (int k0 = 0; k0 < 1024; k0 += 32) {
    const bf16x8 a = *(const bf16x8*)(kv_bf + arow*1024 + k0 + q*8);
    #pragma unroll
    for (int nt = 0; nt < 4; ++nt) {
      const int n = h*64 + nt*16 + l15;
      const bf16x8 bfr = *(const bf16x8*)(Wt + n*1024 + k0 + q*8);
      acc[nt] = __builtin_amdgcn_mfma_f32_16x16x32_bf16(a, bfr, acc[nt], 0, 0, 0);
    }
  }
  #pragma unroll
  for (int nt = 0; nt < 4; ++nt) {
    const int d = nt*16 + l15;
    #pragma unroll
    for (int r = 0; r < 4; ++r) {
      const int row = m0 + q*4 + r;
      if (row < 616) {
        const int b = (int)(((unsigned)row * 54472u) >> 22);   // row/77
        const int s = row - b*77;
        if (isK) K_ws[((b*8 + h)*80 + s)*64 + d] = f2bf(acc[nt][r]);
        else     V_ws[((b*8 + h)*64 + d)*96 + s] = f2bf(acc[nt][r]);
      }
    }
  }
}

// ---------------------------------------------------------------------------
// attn: fused Q-proj + attention + out-proj. Block = (b, 64 tokens).
//   stage X once -> X frags in registers (40 VGPR/lane) -> X LDS region
//   reused for K/V/P/O. Per head: Qproj(40 MFMA/wave) -> q_lds -> QK^T ->
//   shfl softmax -> P -> PV -> o_lds -> out-proj accumulate.
// ---------------------------------------------------------------------------
__global__ __launch_bounds__(256, 2) void attn_kernel(
    const float* __restrict__ query, const short* __restrict__ Wq_t,
    const short* __restrict__ K_ws, const short* __restrict__ V_ws,
    const short* __restrict__ Wo_t, const float* __restrict__ bo,
    float* __restrict__ out) {
  const int n0 = blockIdx.x * 64;
  const int b  = blockIdx.y;
  const int t = threadIdx.x, w = t >> 6, lane = t & 63;
  const int l15 = lane & 15, q = lane >> 4;

  __shared__ short smem[28288];           // 56576 B -> 2 blocks/CU
  short* k_lds = smem;                    // [80][72]   = 5760
  short* v_lds = smem + 5760;             // [64][104]  = 6656
  short* o_lds = smem + 12416;            // [64][72]   = 4608
  short* p_lds = smem + 17024;            // 4x[16][104]= 6656
  short* q_lds = smem + 23680;            // 4x[16][72] = 4608
  short* X_lds = smem;                    // phase-1 overlay: [64][330] = 21120
  short* pw = p_lds + w * 16 * 104;
  short* qw = q_lds + w * 16 * 72;

  // ---- stage X (bf16 transpose): coalesced global, 2-way-free LDS writes ----
  {
    const int tok = t & 63, cb = t >> 6;
    for (int i = 0; i < 80; ++i) {
      const int c = cb + i*4;
      X_lds[tok*XSTR + c] = f2bf(query[((size_t)(b*CC + c))*NN + n0 + tok]);
    }
  }
  __syncthreads();
  // ---- hoist this wave's X fragments (16 tok x 320 k) into registers ----
  bf16x8 xf[10];
  #pragma unroll
  for (int kk = 0; kk < 10; ++kk)
    xf[kk] = ld_frag4(X_lds + (w*16 + l15)*XSTR + kk*32 + q*8);
  __syncthreads();   // all waves done with X region; K/V/P/O may overwrite

  // zero own P region once (s>=77 stays 0 across all heads)
  for (int i = lane; i < 832; i += 64) ((unsigned*)pw)[i] = 0u;

  const f32x4 z = {0.f, 0.f, 0.f, 0.f};
  f32x4 outacc[5][4];
  #pragma unroll
  for (int mt = 0; mt < 5; ++mt)
    #pragma unroll
    for (int nt = 0; nt < 4; ++nt) outacc[mt][nt] = z;

  for (int h = 0; h < HEADS; ++h) {
    if (h) __syncthreads();   // protect k/v/o overwrite from previous head
    {  // stage K (80x64) and V^T (64x96) for this (b,h)
      const short* Ksrc = K_ws + (size_t)(b*8 + h) * 80 * 64;
      #pragma unroll
      for (int i = 0; i < 5; ++i) {
        const int idx4 = (i*256 + t) * 4;
        const int s = idx4 >> 6, d = idx4 & 63;
        *(s16x4*)(k_lds + s*72 + d) = *(const s16x4*)(Ksrc + idx4);
      }
      const short* Vsrc = V_ws + (size_t)(b*8 + h) * 64 * 96;
      const int row = t >> 2;
      #pragma unroll
      for (int i = 0; i < 6; ++i) {
        const int col = (t & 3) * 24 + i * 4;
        *(s16x4*)(v_lds + row*104 + col) = *(const s16x4*)(Vsrc + row*96 + col);
      }
    }
    __syncthreads();   // staging done

    // ---- Q-proj: D[tok16][d64] from register-X x Wq_t (L2) ----
    f32x4 qa[4] = {z, z, z, z};
    #pragma unroll
    for (int kk = 0; kk < 10; ++kk) {
      #pragma unroll
      for (int nt = 0; nt < 4; ++nt) {
        const bf16x8 bfr = *(const bf16x8*)(Wq_t + (h*64 + nt*16 + l15)*320 + kk*32 + q*8);
        qa[nt] = __builtin_amdgcn_mfma_f32_16x16x32_bf16(xf[kk], bfr, qa[nt], 0, 0, 0);
      }
    }
    #pragma unroll
    for (int nt = 0; nt < 4; ++nt)
      #pragma unroll
      for (int r = 0; r < 4; ++r)
        qw[(q*4 + r)*72 + nt*16 + l15] = f2bf(qa[nt][r]);
    // (same-wave LDS RAW: compiler inserts lgkmcnt wait)

    // ---- QK^T: D[s][tok] ----
    f32x4 qk[5] = {z, z, z, z, z};
    #pragma unroll
    for (int ks = 0; ks < 2; ++ks) {
      const bf16x8 bq = *(const bf16x8*)(qw + l15*72 + ks*32 + q*8);
      #pragma unroll
      for (int mt = 0; mt < 5; ++mt) {
        const bf16x8 a = *(const bf16x8*)(k_lds + (mt*16 + l15)*72 + ks*32 + q*8);
        qk[mt] = __builtin_amdgcn_mfma_f32_16x16x32_bf16(a, bq, qk[mt], 0, 0, 0);
      }
    }

    // ---- softmax over s via quad shuffles ----
    float mx = -1e30f;
    #pragma unroll
    for (int mt = 0; mt < 5; ++mt)
      #pragma unroll
      for (int r = 0; r < 4; ++r) {
        const int s = mt*16 + q*4 + r;
        const float vv = (s < 77) ? qk[mt][r] * SCALE : -1e30f;
        qk[mt][r] = vv;
        mx = fmaxf(mx, vv);
      }
    mx = fmaxf(mx, __shfl_xor(mx, 16));
    mx = fmaxf(mx, __shfl_xor(mx, 32));
    float sum = 0.f;
    #pragma unroll
    for (int mt = 0; mt < 5; ++mt)
      #pragma unroll
      for (int r = 0; r < 4; ++r) {
        const int s = mt*16 + q*4 + r;
        const float e = (s < 77) ? __expf(qk[mt][r] - mx) : 0.f;
        qk[mt][r] = e;
        sum += e;
      }
    sum += __shfl_xor(sum, 16);
    sum += __shfl_xor(sum, 32);
    const float inv = 1.0f / sum;
    #pragma unroll
    for (int mt = 0; mt < 5; ++mt)
      #pragma unroll
      for (int r = 0; r < 4; ++r) {
        const int s = mt*16 + q*4 + r;
        if (s < 77) pw[l15*104 + s] = f2bf(qk[mt][r] * inv);
      }

    // ---- PV: D[d][tok] ----
    f32x4 ov[4] = {z, z, z, z};
    #pragma unroll
    for (int ks = 0; ks < 3; ++ks) {
      const bf16x8 bp = *(const bf16x8*)(pw + l15*104 + ks*32 + q*8);
      #pragma unroll
      for (int mt = 0; mt < 4; ++mt) {
        const bf16x8 a = *(const bf16x8*)(v_lds + (mt*16 + l15)*104 + ks*32 + q*8);
        ov[mt] = __builtin_amdgcn_mfma_f32_16x16x32_bf16(a, bp, ov[mt], 0, 0, 0);
      }
    }
    #pragma unroll
    for (int mt = 0; mt < 4; ++mt)
      #pragma unroll
      for (int r = 0; r < 4; ++r)
        o_lds[(w*16 + l15)*72 + mt*16 + q*4 + r] = f2bf(ov[mt][r]);
    __syncthreads();   // O assembled across waves

    // ---- out-proj accumulate: wave w -> channels w*80..w*80+79 ----
    #pragma unroll
    for (int ks = 0; ks < 2; ++ks) {
      bf16x8 bfrag[4];
      #pragma unroll
      for (int nt = 0; nt < 4; ++nt)
        bfrag[nt] = *(const bf16x8*)(o_lds + (nt*16 + l15)*72 + ks*32 + q*8);
      #pragma unroll
      for (int mt = 0; mt < 5; ++mt) {
        const int c = w*80 + mt*16 + l15;
        const bf16x8 a = *(const bf16x8*)(Wo_t + c*512 + h*64 + ks*32 + q*8);
        #pragma unroll
        for (int nt = 0; nt < 4; ++nt)
          outacc[mt][nt] = __builtin_amdgcn_mfma_f32_16x16x32_bf16(a, bfrag[nt], outacc[mt][nt], 0, 0, 0);
      }
    }
  }

  // ---- epilogue: bias + store out[b][c][n0+tok] ----
  #pragma unroll
  for (int mt = 0; mt < 5; ++mt)
    #pragma unroll
    for (int r = 0; r < 4; ++r) {
      const int c = w*80 + mt*16 + q*4 + r;
      const float bv = bo[c];
      #pragma unroll
      for (int nt = 0; nt < 4; ++nt)
        out[((size_t)(b*CC + c))*NN + n0 + nt*16 + l15] = outacc[mt][nt][r] + bv;
    }
}

// ---------------------------------------------------------------------------
extern "C" void kernel_launch(void* const* d_in, const int* in_sizes, int n_in,
                              void* d_out, int out_size, void* d_ws, size_t ws_size,
                              hipStream_t stream) {
  const float* query = (const float*)d_in[0];
  const float* kv    = (const float*)d_in[1];
  const float* Wq    = (const float*)d_in[2];
  const float* Wk    = (const float*)d_in[3];
  const float* Wv    = (const float*)d_in[4];
  const float* Wo    = (const float*)d_in[5];
  const float* bo    = (const float*)d_in[6];
  float* out = (float*)d_out;

  char* p = (char*)d_ws;
  short* K_ws  = (short*)(p);             //   819,200 B [8][8][80][64]
  short* V_ws  = (short*)(p +   819200);  //   983,040 B [8][8][64][96]
  short* kv_bf = (short*)(p +  1802240);  // 1,261,568 B [616][1024]
  short* Wk_t  = (short*)(p +  3063808);  // 1,048,576 B [512][1024]
  short* Wv_t  = (short*)(p +  4112384);  // 1,048,576 B [512][1024]
  short* Wq_t  = (short*)(p +  5160960);  //   327,680 B [512][320]
  short* Wo_t  = (short*)(p +  5488640);  //   327,680 B [320][512]

  prep_kernel<<<2144, 256, 0, stream>>>(kv, Wk, Wv, Wq, Wo, kv_bf, Wk_t, Wv_t,
                                        Wq_t, Wo_t, (unsigned*)p);
  kvproj_kernel<<<dim3(10, 16), 256, 0, stream>>>(kv_bf, Wk_t, Wv_t, K_ws, V_ws);
  attn_kernel<<<dim3(64, 8), 256, 0, stream>>>(query, Wq_t, K_ws, V_ws, Wo_t, bo, out);
}